// Round 6
// baseline (1150.765 us; speedup 1.0000x reference)
//
#include <hip/hip_runtime.h>
#include <math.h>

#define H 2048
#define R (4 * H)              // 8192 rows per weight matrix
#define L 3
#define NBLK 1024              // 4 blocks/CU, 16/32 waves/CU — co-resident by capacity
#define NWAVE (NBLK * 4)       // 4096 waves
#define ROWS_P1 (R + L * R)    // 32768 rows in phase 1
#define RPW_P1 (ROWS_P1 / NWAVE)   // 8 rows/wave
#define RPW_WIX (R / NWAVE)        // 2 rows/wave
#define NBAR 8                 // barrier slots (5 used)

// Native clang vector type — __builtin_nontemporal_load rejects HIP's float4.
typedef float f4 __attribute__((ext_vector_type(4)));

// ---------------------------------------------------------------------------
// Manual device-scope grid barrier (graph-capture-safe; no cooperative API).
// Correct only because all NBLK blocks are co-resident (4 blocks/CU, ~64 VGPR,
// 0 LDS). Release: threadfence + device-scope atomicAdd. Acquire: atomic spin
// read + per-thread threadfence after syncthreads (invalidates L1 across XCDs).
// ---------------------------------------------------------------------------
__device__ __forceinline__ void grid_barrier(unsigned* __restrict__ bar, int i) {
    __syncthreads();
    if (threadIdx.x == 0) {
        __threadfence();                       // release: publish our writes
        atomicAdd(&bar[i], 1u);
        while (atomicAdd(&bar[i], 0u) < (unsigned)NBLK)
            __builtin_amdgcn_s_sleep(8);
    }
    __syncthreads();
    __threadfence();                           // acquire in every thread
}

__global__ void init_barriers(unsigned* __restrict__ bar) {
    if (threadIdx.x < NBAR) bar[threadIdx.x] = 0u;
}

// ---------------------------------------------------------------------------
// Wave-per-row GEMV dot: 8 coalesced float4 loads/lane (8 KB/wave), weights
// streamed nontemporal, vector cache-resident. Wave-private shuffle reduce —
// no LDS, no __syncthreads. Dual accumulators halve the dependent-FMA chain.
// ---------------------------------------------------------------------------
__device__ __forceinline__ float wave_row_dot(const float* __restrict__ row,
                                              const float* __restrict__ vec,
                                              int lane) {
    const f4* r4 = (const f4*)row;
    const f4* v4 = (const f4*)vec;
    float acc0 = 0.f, acc1 = 0.f;
#pragma unroll
    for (int it = 0; it < (H / 4) / 128; ++it) {   // 4 iterations of 2 chains
        const int i0 = (2 * it) * 64 + lane;
        const int i1 = (2 * it + 1) * 64 + lane;
        f4 a0 = __builtin_nontemporal_load(r4 + i0);
        f4 a1 = __builtin_nontemporal_load(r4 + i1);
        f4 v0 = v4[i0];
        f4 v1 = v4[i1];
        acc0 = fmaf(a0.x, v0.x, acc0);
        acc1 = fmaf(a1.x, v1.x, acc1);
        acc0 = fmaf(a0.y, v0.y, acc0);
        acc1 = fmaf(a1.y, v1.y, acc1);
        acc0 = fmaf(a0.z, v0.z, acc0);
        acc1 = fmaf(a1.z, v1.z, acc1);
        acc0 = fmaf(a0.w, v0.w, acc0);
        acc1 = fmaf(a1.w, v1.w, acc1);
    }
    float acc = acc0 + acc1;
#pragma unroll
    for (int off = 32; off > 0; off >>= 1)
        acc += __shfl_down(acc, off);
    return acc;   // lane 0 holds the row dot
}

// Elementwise LSTM cell update for one output index j.
__device__ __forceinline__ void lstm_update_elem(const float* __restrict__ pre_l,
                                                 const float* __restrict__ xpart,
                                                 const float* __restrict__ c0_l,
                                                 float* __restrict__ h_out,
                                                 int j) {
    const float gi = pre_l[j]         + xpart[j];
    const float gf = pre_l[H + j]     + xpart[H + j];
    const float gg = pre_l[2 * H + j] + xpart[2 * H + j];
    const float go = pre_l[3 * H + j] + xpart[3 * H + j];

    const float i_ = 1.f / (1.f + expf(-gi));
    const float f_ = 1.f / (1.f + expf(-gf));
    const float g_ = tanhf(gg);
    const float o_ = 1.f / (1.f + expf(-go));

    const float c_new = f_ * c0_l[j] + i_ * g_;
    h_out[j] = o_ * tanhf(c_new);
}

// ---------------------------------------------------------------------------
// Single persistent kernel: P1 |bar| U0 |bar| P2 |bar| U1 |bar| P3 |bar| U2.
// Kills all 6 inter-kernel launch gaps.
// ---------------------------------------------------------------------------
__global__ __launch_bounds__(256) void fused_lstm_kernel(
    const float* __restrict__ Wi,    // [L*R, H]
    const float* __restrict__ Wh,    // [L*R, H]
    const float* __restrict__ bi,    // [L*R]
    const float* __restrict__ bh,    // [L*R]
    const float* __restrict__ x,     // [H]
    const float* __restrict__ h0,    // [L, H]
    const float* __restrict__ c0,    // [L, H]
    float* __restrict__ xpart,       // [R]
    float* __restrict__ pre,         // [L*R]
    float* __restrict__ xbuf1,       // [H]
    float* __restrict__ xbuf2,       // [H]
    unsigned* __restrict__ bar,      // [NBAR]
    float* __restrict__ out)         // [H]
{
    const int wid  = threadIdx.x >> 6;
    const int lane = threadIdx.x & 63;
    const int w    = blockIdx.x * 4 + wid;          // wave id in [0, NWAVE)
    const int tid  = blockIdx.x * 256 + threadIdx.x;

    // ---- Phase 1: Wi[0]@x and all Wh[l]@h0[l] (+biases). 268 MB. ----
#pragma unroll
    for (int k = 0; k < RPW_P1; ++k) {
        const int g = w * RPW_P1 + k;               // [0, 32768)
        const float* row;
        const float* vec;
        if (g < R) {
            row = Wi + (size_t)g * H;
            vec = x;
        } else {
            const int r = g - R;
            row = Wh + (size_t)r * H;
            vec = h0 + (r >> 13) * H;               // l = r / 8192
        }
        const float tot = wave_row_dot(row, vec, lane);
        if (lane == 0) {
            if (g < R) {
                xpart[g] = tot;
            } else {
                const int r = g - R;
                pre[r] = tot + bi[r] + bh[r];
            }
        }
    }
    grid_barrier(bar, 0);

    // ---- Update layer 0 -> xbuf1 ----
    if (tid < H) lstm_update_elem(pre, xpart, c0, xbuf1, tid);
    grid_barrier(bar, 1);

    // ---- Phase 2: Wi[1] @ xbuf1. 67 MB. ----
#pragma unroll
    for (int k = 0; k < RPW_WIX; ++k) {
        const int g = w * RPW_WIX + k;              // [0, R)
        const float tot = wave_row_dot(Wi + (size_t)R * H + (size_t)g * H, xbuf1, lane);
        if (lane == 0) xpart[g] = tot;
    }
    grid_barrier(bar, 2);

    // ---- Update layer 1 -> xbuf2 ----
    if (tid < H) lstm_update_elem(pre + R, xpart, c0 + H, xbuf2, tid);
    grid_barrier(bar, 3);

    // ---- Phase 3: Wi[2] @ xbuf2. 67 MB. ----
#pragma unroll
    for (int k = 0; k < RPW_WIX; ++k) {
        const int g = w * RPW_WIX + k;
        const float tot = wave_row_dot(Wi + 2 * (size_t)R * H + (size_t)g * H, xbuf2, lane);
        if (lane == 0) xpart[g] = tot;
    }
    grid_barrier(bar, 4);

    // ---- Update layer 2 -> out ----
    if (tid < H) lstm_update_elem(pre + 2 * R, xpart, c0 + 2 * H, out, tid);
}

extern "C" void kernel_launch(void* const* d_in, const int* in_sizes, int n_in,
                              void* d_out, int out_size, void* d_ws, size_t ws_size,
                              hipStream_t stream) {
    const float* x    = (const float*)d_in[0];  // [H]
    const float* W_ih = (const float*)d_in[1];  // [L, R, H]
    const float* W_hh = (const float*)d_in[2];  // [L, R, H]
    const float* b_ih = (const float*)d_in[3];  // [L, R]
    const float* b_hh = (const float*)d_in[4];  // [L, R]
    const float* h0   = (const float*)d_in[5];  // [L, H]
    const float* c0   = (const float*)d_in[6];  // [L, H]
    float* out = (float*)d_out;                 // [H]

    float* xpart = (float*)d_ws;                // [R]
    float* pre   = xpart + R;                   // [L*R]
    float* xbuf1 = pre + L * R;                 // [H]
    float* xbuf2 = xbuf1 + H;                   // [H]
    unsigned* bar = (unsigned*)(xbuf2 + H);     // [NBAR]

    // Zero barrier counters; stream order guarantees completion before the
    // fused kernel starts. Regular launches only — graph-capture-safe.
    init_barriers<<<1, 64, 0, stream>>>(bar);

    fused_lstm_kernel<<<NBLK, 256, 0, stream>>>(
        W_ih, W_hh, b_ih, b_hh, x, h0, c0,
        xpart, pre, xbuf1, xbuf2, bar, out);
}

// Round 7
// 1063.166 us; speedup vs baseline: 1.0824x; 1.0824x over previous
//
#include <hip/hip_runtime.h>
#include <math.h>

#define H 2048
#define R (4 * H)              // 8192 rows per weight matrix
#define L 3
#define NBLK 1024              // 4 blocks/CU, 16/32 waves/CU — co-resident by capacity
#define NWAVE (NBLK * 4)       // 4096 waves
#define ROWS_P1 (R + L * R)    // 32768 rows in phase 1
#define RPW_P1 (ROWS_P1 / NWAVE)   // 8 rows/wave
#define RPW_WIX (R / NWAVE)        // 2 rows/wave
#define NBAR 5                 // barrier slots used
#define BAR_STRIDE 64          // uints per slot: count at +0, flag at +32 (128B apart)

// Native clang vector type — __builtin_nontemporal_load rejects HIP's float4.
typedef float f4 __attribute__((ext_vector_type(4)));

// ---------------------------------------------------------------------------
// Manual device-scope grid barrier, v2. Round-6 post-mortem: polling with
// atomicAdd(ptr,0) (an RMW) from 1024 blocks serialized on one line and made
// the kernel 99% idle (VALUBusy 0.7%). Fix: arrival = one RMW per block on a
// count line; release = agent-scope store to a FLAG on a separate 128B line;
// waiters poll the flag with plain atomic LOADS + s_sleep backoff. Correct
// only because all NBLK blocks are co-resident (4 blocks/CU, 40 VGPR, 0 LDS).
// ---------------------------------------------------------------------------
__device__ __forceinline__ void grid_barrier(unsigned* __restrict__ bar, int slot) {
    unsigned* cnt  = bar + slot * BAR_STRIDE;
    unsigned* flag = bar + slot * BAR_STRIDE + 32;
    __syncthreads();
    if (threadIdx.x == 0) {
        __threadfence();                       // release: publish our writes
        const unsigned prev = atomicAdd(cnt, 1u);   // device-scope by default
        if (prev == (unsigned)(NBLK - 1)) {
            __hip_atomic_store(flag, 1u, __ATOMIC_RELEASE, __HIP_MEMORY_SCOPE_AGENT);
        } else {
            while (__hip_atomic_load(flag, __ATOMIC_ACQUIRE,
                                     __HIP_MEMORY_SCOPE_AGENT) == 0u)
                __builtin_amdgcn_s_sleep(16);  // ~0.43 µs backoff per poll
        }
    }
    __syncthreads();
    __threadfence();                           // acquire in every thread
}

__global__ void init_barriers(unsigned* __restrict__ bar) {
    const int i = blockIdx.x * blockDim.x + threadIdx.x;
    if (i < NBAR * BAR_STRIDE) bar[i] = 0u;
}

// ---------------------------------------------------------------------------
// Wave-per-row GEMV dot: 8 coalesced float4 loads/lane (8 KB/wave), weights
// streamed nontemporal, vector cache-resident. Wave-private shuffle reduce —
// no LDS, no __syncthreads. Dual accumulators halve the dependent-FMA chain.
// ---------------------------------------------------------------------------
__device__ __forceinline__ float wave_row_dot(const float* __restrict__ row,
                                              const float* __restrict__ vec,
                                              int lane) {
    const f4* r4 = (const f4*)row;
    const f4* v4 = (const f4*)vec;
    float acc0 = 0.f, acc1 = 0.f;
#pragma unroll
    for (int it = 0; it < (H / 4) / 128; ++it) {   // 4 iterations of 2 chains
        const int i0 = (2 * it) * 64 + lane;
        const int i1 = (2 * it + 1) * 64 + lane;
        f4 a0 = __builtin_nontemporal_load(r4 + i0);
        f4 a1 = __builtin_nontemporal_load(r4 + i1);
        f4 v0 = v4[i0];
        f4 v1 = v4[i1];
        acc0 = fmaf(a0.x, v0.x, acc0);
        acc1 = fmaf(a1.x, v1.x, acc1);
        acc0 = fmaf(a0.y, v0.y, acc0);
        acc1 = fmaf(a1.y, v1.y, acc1);
        acc0 = fmaf(a0.z, v0.z, acc0);
        acc1 = fmaf(a1.z, v1.z, acc1);
        acc0 = fmaf(a0.w, v0.w, acc0);
        acc1 = fmaf(a1.w, v1.w, acc1);
    }
    float acc = acc0 + acc1;
#pragma unroll
    for (int off = 32; off > 0; off >>= 1)
        acc += __shfl_down(acc, off);
    return acc;   // lane 0 holds the row dot
}

// Elementwise LSTM cell update for one output index j.
__device__ __forceinline__ void lstm_update_elem(const float* __restrict__ pre_l,
                                                 const float* __restrict__ xpart,
                                                 const float* __restrict__ c0_l,
                                                 float* __restrict__ h_out,
                                                 int j) {
    const float gi = pre_l[j]         + xpart[j];
    const float gf = pre_l[H + j]     + xpart[H + j];
    const float gg = pre_l[2 * H + j] + xpart[2 * H + j];
    const float go = pre_l[3 * H + j] + xpart[3 * H + j];

    const float i_ = 1.f / (1.f + expf(-gi));
    const float f_ = 1.f / (1.f + expf(-gf));
    const float g_ = tanhf(gg);
    const float o_ = 1.f / (1.f + expf(-go));

    const float c_new = f_ * c0_l[j] + i_ * g_;
    h_out[j] = o_ * tanhf(c_new);
}

// ---------------------------------------------------------------------------
// Single persistent kernel: P1 |bar| U0 |bar| P2 |bar| U1 |bar| P3 |bar| U2.
// ---------------------------------------------------------------------------
__global__ __launch_bounds__(256) void fused_lstm_kernel(
    const float* __restrict__ Wi,    // [L*R, H]
    const float* __restrict__ Wh,    // [L*R, H]
    const float* __restrict__ bi,    // [L*R]
    const float* __restrict__ bh,    // [L*R]
    const float* __restrict__ x,     // [H]
    const float* __restrict__ h0,    // [L, H]
    const float* __restrict__ c0,    // [L, H]
    float* __restrict__ xpart,       // [R]
    float* __restrict__ pre,         // [L*R]
    float* __restrict__ xbuf1,       // [H]
    float* __restrict__ xbuf2,       // [H]
    unsigned* __restrict__ bar,      // [NBAR * BAR_STRIDE]
    float* __restrict__ out)         // [H]
{
    const int wid  = threadIdx.x >> 6;
    const int lane = threadIdx.x & 63;
    const int w    = blockIdx.x * 4 + wid;          // wave id in [0, NWAVE)
    const int tid  = blockIdx.x * 256 + threadIdx.x;

    // ---- Phase 1: Wi[0]@x and all Wh[l]@h0[l] (+biases). 268 MB. ----
#pragma unroll
    for (int k = 0; k < RPW_P1; ++k) {
        const int g = w * RPW_P1 + k;               // [0, 32768)
        const float* row;
        const float* vec;
        if (g < R) {
            row = Wi + (size_t)g * H;
            vec = x;
        } else {
            const int r = g - R;
            row = Wh + (size_t)r * H;
            vec = h0 + (r >> 13) * H;               // l = r / 8192
        }
        const float tot = wave_row_dot(row, vec, lane);
        if (lane == 0) {
            if (g < R) {
                xpart[g] = tot;
            } else {
                const int r = g - R;
                pre[r] = tot + bi[r] + bh[r];
            }
        }
    }
    grid_barrier(bar, 0);

    // ---- Update layer 0 -> xbuf1 ----
    if (tid < H) lstm_update_elem(pre, xpart, c0, xbuf1, tid);
    grid_barrier(bar, 1);

    // ---- Phase 2: Wi[1] @ xbuf1. 67 MB. ----
#pragma unroll
    for (int k = 0; k < RPW_WIX; ++k) {
        const int g = w * RPW_WIX + k;              // [0, R)
        const float tot = wave_row_dot(Wi + (size_t)R * H + (size_t)g * H, xbuf1, lane);
        if (lane == 0) xpart[g] = tot;
    }
    grid_barrier(bar, 2);

    // ---- Update layer 1 -> xbuf2 ----
    if (tid < H) lstm_update_elem(pre + R, xpart, c0 + H, xbuf2, tid);
    grid_barrier(bar, 3);

    // ---- Phase 3: Wi[2] @ xbuf2. 67 MB. ----
#pragma unroll
    for (int k = 0; k < RPW_WIX; ++k) {
        const int g = w * RPW_WIX + k;
        const float tot = wave_row_dot(Wi + 2 * (size_t)R * H + (size_t)g * H, xbuf2, lane);
        if (lane == 0) xpart[g] = tot;
    }
    grid_barrier(bar, 4);

    // ---- Update layer 2 -> out ----
    if (tid < H) lstm_update_elem(pre + 2 * R, xpart, c0 + 2 * H, out, tid);
}

extern "C" void kernel_launch(void* const* d_in, const int* in_sizes, int n_in,
                              void* d_out, int out_size, void* d_ws, size_t ws_size,
                              hipStream_t stream) {
    const float* x    = (const float*)d_in[0];  // [H]
    const float* W_ih = (const float*)d_in[1];  // [L, R, H]
    const float* W_hh = (const float*)d_in[2];  // [L, R, H]
    const float* b_ih = (const float*)d_in[3];  // [L, R]
    const float* b_hh = (const float*)d_in[4];  // [L, R]
    const float* h0   = (const float*)d_in[5];  // [L, H]
    const float* c0   = (const float*)d_in[6];  // [L, H]
    float* out = (float*)d_out;                 // [H]

    float* xpart = (float*)d_ws;                // [R]
    float* pre   = xpart + R;                   // [L*R]
    float* xbuf1 = pre + L * R;                 // [H]
    float* xbuf2 = xbuf1 + H;                   // [H]
    unsigned* bar = (unsigned*)(xbuf2 + H);     // [NBAR * BAR_STRIDE]

    // Zero barrier counters; stream order guarantees completion before the
    // fused kernel starts. Regular launches only — graph-capture-safe.
    init_barriers<<<1, NBAR * BAR_STRIDE, 0, stream>>>(bar);

    fused_lstm_kernel<<<NBLK, 256, 0, stream>>>(
        W_ih, W_hh, b_ih, b_hh, x, h0, c0,
        xpart, pre, xbuf1, xbuf2, bar, out);
}

// Round 8
// 677.603 us; speedup vs baseline: 1.6983x; 1.5690x over previous
//
#include <hip/hip_runtime.h>
#include <math.h>

#define H 2048
#define R (4 * H)              // 8192 rows per weight matrix
#define L 3
#define NBLK 1024              // 4 blocks/CU, 16/32 waves/CU — co-resident by capacity
#define NWAVE (NBLK * 4)       // 4096 waves
#define ROWS_P1 (R + L * R)    // 32768 rows in phase 1
#define RPW_P1 (ROWS_P1 / NWAVE)   // 8 rows/wave
#define RPW_WIX (R / NWAVE)        // 2 rows/wave
#define NBAR 5                 // barrier slots used
#define BAR_WORDS (NBLK + 64)  // per-barrier: arr[NBLK] then flag on its own line

// Native clang vector type — __builtin_nontemporal_load rejects HIP's float4.
typedef float f4 __attribute__((ext_vector_type(4)));

// ---------------------------------------------------------------------------
// Manual grid barrier, v3. R6/R7 post-mortem: v1/v2 spent ~140 µs per barrier
// with VALUBusy 0.7%. Surviving suspects in both: (a) 1024 serialized
// same-address atomicAdd arrivals, (b) acquire-loads in the poll loop (per-poll
// L1/L2 invalidate on non-coherent XCDs), (c) exit __threadfence in all 4
// waves per block. v3: per-block SLOT stores (parallel, no RMW chain); master
// block detects via relaxed loads; waiters poll flag with RELAXED loads
// (invalidate-free spinning); ONE acquire __threadfence per block (L1 is
// CU-shared, L2 XCD-shared — one buffer_inv covers all waves in the block).
// Ordering = fence-based synchronization through relaxed atomics:
//   block: F_rel; W slot.  master: R slots; F; W flag.  waiter: R flag; F; reads.
// Correct only because all NBLK blocks are co-resident (4/CU, 40 VGPR, 0 LDS).
// ---------------------------------------------------------------------------
__device__ __forceinline__ void grid_barrier(unsigned* __restrict__ bar, int slot) {
    unsigned* arr  = bar + slot * BAR_WORDS;
    unsigned* flag = arr + NBLK + 16;            // separate 64B line
    __syncthreads();
    if (threadIdx.x == 0) {
        __threadfence();                         // release: publish phase writes
        __hip_atomic_store(&arr[blockIdx.x], 1u,
                           __ATOMIC_RELAXED, __HIP_MEMORY_SCOPE_AGENT);
    }
    if (blockIdx.x == 0) {
        // Master: 256 threads each watch 4 consecutive slot words (1 line).
        const int base = threadIdx.x * 4;
#pragma unroll
        for (int k = 0; k < 4; ++k) {
            while (__hip_atomic_load(&arr[base + k], __ATOMIC_RELAXED,
                                     __HIP_MEMORY_SCOPE_AGENT) == 0u)
                __builtin_amdgcn_s_sleep(1);
        }
        __syncthreads();                         // all 1024 arrivals observed
        if (threadIdx.x == 0) {
            __threadfence();                     // pairs releases -> flag store
            __hip_atomic_store(flag, 1u,
                               __ATOMIC_RELAXED, __HIP_MEMORY_SCOPE_AGENT);
        }
        __syncthreads();                         // thread0's inv covers the block
    } else {
        if (threadIdx.x == 0) {
            while (__hip_atomic_load(flag, __ATOMIC_RELAXED,
                                     __HIP_MEMORY_SCOPE_AGENT) == 0u)
                __builtin_amdgcn_s_sleep(16);    // invalidate-free spin
            __threadfence();                     // acquire ONCE per block
        }
        __syncthreads();                         // then all waves read fresh
    }
}

__global__ void init_barriers(unsigned* __restrict__ bar) {
    const int n = NBAR * BAR_WORDS;
    for (int i = blockIdx.x * blockDim.x + threadIdx.x; i < n;
         i += gridDim.x * blockDim.x)
        bar[i] = 0u;
}

// ---------------------------------------------------------------------------
// Wave-per-row GEMV dot: 8 coalesced float4 loads/lane (8 KB/wave), weights
// streamed nontemporal, vector cache-resident. Wave-private shuffle reduce —
// no LDS, no __syncthreads. Dual accumulators halve the dependent-FMA chain.
// ---------------------------------------------------------------------------
__device__ __forceinline__ float wave_row_dot(const float* __restrict__ row,
                                              const float* __restrict__ vec,
                                              int lane) {
    const f4* r4 = (const f4*)row;
    const f4* v4 = (const f4*)vec;
    float acc0 = 0.f, acc1 = 0.f;
#pragma unroll
    for (int it = 0; it < (H / 4) / 128; ++it) {   // 4 iterations of 2 chains
        const int i0 = (2 * it) * 64 + lane;
        const int i1 = (2 * it + 1) * 64 + lane;
        f4 a0 = __builtin_nontemporal_load(r4 + i0);
        f4 a1 = __builtin_nontemporal_load(r4 + i1);
        f4 v0 = v4[i0];
        f4 v1 = v4[i1];
        acc0 = fmaf(a0.x, v0.x, acc0);
        acc1 = fmaf(a1.x, v1.x, acc1);
        acc0 = fmaf(a0.y, v0.y, acc0);
        acc1 = fmaf(a1.y, v1.y, acc1);
        acc0 = fmaf(a0.z, v0.z, acc0);
        acc1 = fmaf(a1.z, v1.z, acc1);
        acc0 = fmaf(a0.w, v0.w, acc0);
        acc1 = fmaf(a1.w, v1.w, acc1);
    }
    float acc = acc0 + acc1;
#pragma unroll
    for (int off = 32; off > 0; off >>= 1)
        acc += __shfl_down(acc, off);
    return acc;   // lane 0 holds the row dot
}

// Elementwise LSTM cell update for one output index j.
__device__ __forceinline__ void lstm_update_elem(const float* __restrict__ pre_l,
                                                 const float* __restrict__ xpart,
                                                 const float* __restrict__ c0_l,
                                                 float* __restrict__ h_out,
                                                 int j) {
    const float gi = pre_l[j]         + xpart[j];
    const float gf = pre_l[H + j]     + xpart[H + j];
    const float gg = pre_l[2 * H + j] + xpart[2 * H + j];
    const float go = pre_l[3 * H + j] + xpart[3 * H + j];

    const float i_ = 1.f / (1.f + expf(-gi));
    const float f_ = 1.f / (1.f + expf(-gf));
    const float g_ = tanhf(gg);
    const float o_ = 1.f / (1.f + expf(-go));

    const float c_new = f_ * c0_l[j] + i_ * g_;
    h_out[j] = o_ * tanhf(c_new);
}

// ---------------------------------------------------------------------------
// Single persistent kernel: P1 |bar| U0 |bar| P2 |bar| U1 |bar| P3 |bar| U2.
// ---------------------------------------------------------------------------
__global__ __launch_bounds__(256) void fused_lstm_kernel(
    const float* __restrict__ Wi,    // [L*R, H]
    const float* __restrict__ Wh,    // [L*R, H]
    const float* __restrict__ bi,    // [L*R]
    const float* __restrict__ bh,    // [L*R]
    const float* __restrict__ x,     // [H]
    const float* __restrict__ h0,    // [L, H]
    const float* __restrict__ c0,    // [L, H]
    float* __restrict__ xpart,       // [R]
    float* __restrict__ pre,         // [L*R]
    float* __restrict__ xbuf1,       // [H]
    float* __restrict__ xbuf2,       // [H]
    unsigned* __restrict__ bar,      // [NBAR * BAR_WORDS]
    float* __restrict__ out)         // [H]
{
    const int wid  = threadIdx.x >> 6;
    const int lane = threadIdx.x & 63;
    const int w    = blockIdx.x * 4 + wid;          // wave id in [0, NWAVE)
    const int tid  = blockIdx.x * 256 + threadIdx.x;

    // ---- Phase 1: Wi[0]@x and all Wh[l]@h0[l] (+biases). 268 MB. ----
#pragma unroll
    for (int k = 0; k < RPW_P1; ++k) {
        const int g = w * RPW_P1 + k;               // [0, 32768)
        const float* row;
        const float* vec;
        if (g < R) {
            row = Wi + (size_t)g * H;
            vec = x;
        } else {
            const int r = g - R;
            row = Wh + (size_t)r * H;
            vec = h0 + (r >> 13) * H;               // l = r / 8192
        }
        const float tot = wave_row_dot(row, vec, lane);
        if (lane == 0) {
            if (g < R) {
                xpart[g] = tot;
            } else {
                const int r = g - R;
                pre[r] = tot + bi[r] + bh[r];
            }
        }
    }
    grid_barrier(bar, 0);

    // ---- Update layer 0 -> xbuf1 ----
    if (tid < H) lstm_update_elem(pre, xpart, c0, xbuf1, tid);
    grid_barrier(bar, 1);

    // ---- Phase 2: Wi[1] @ xbuf1. 67 MB. ----
#pragma unroll
    for (int k = 0; k < RPW_WIX; ++k) {
        const int g = w * RPW_WIX + k;              // [0, R)
        const float tot = wave_row_dot(Wi + (size_t)R * H + (size_t)g * H, xbuf1, lane);
        if (lane == 0) xpart[g] = tot;
    }
    grid_barrier(bar, 2);

    // ---- Update layer 1 -> xbuf2 ----
    if (tid < H) lstm_update_elem(pre + R, xpart, c0 + H, xbuf2, tid);
    grid_barrier(bar, 3);

    // ---- Phase 3: Wi[2] @ xbuf2. 67 MB. ----
#pragma unroll
    for (int k = 0; k < RPW_WIX; ++k) {
        const int g = w * RPW_WIX + k;
        const float tot = wave_row_dot(Wi + 2 * (size_t)R * H + (size_t)g * H, xbuf2, lane);
        if (lane == 0) xpart[g] = tot;
    }
    grid_barrier(bar, 4);

    // ---- Update layer 2 -> out ----
    if (tid < H) lstm_update_elem(pre + 2 * R, xpart, c0 + 2 * H, out, tid);
}

extern "C" void kernel_launch(void* const* d_in, const int* in_sizes, int n_in,
                              void* d_out, int out_size, void* d_ws, size_t ws_size,
                              hipStream_t stream) {
    const float* x    = (const float*)d_in[0];  // [H]
    const float* W_ih = (const float*)d_in[1];  // [L, R, H]
    const float* W_hh = (const float*)d_in[2];  // [L, R, H]
    const float* b_ih = (const float*)d_in[3];  // [L, R]
    const float* b_hh = (const float*)d_in[4];  // [L, R]
    const float* h0   = (const float*)d_in[5];  // [L, H]
    const float* c0   = (const float*)d_in[6];  // [L, H]
    float* out = (float*)d_out;                 // [H]

    float* xpart = (float*)d_ws;                // [R]
    float* pre   = xpart + R;                   // [L*R]
    float* xbuf1 = pre + L * R;                 // [H]
    float* xbuf2 = xbuf1 + H;                   // [H]
    unsigned* bar = (unsigned*)(xbuf2 + H);     // [NBAR * BAR_WORDS]

    // Zero barrier state; stream order guarantees completion before the
    // fused kernel starts. Regular launches only — graph-capture-safe.
    init_barriers<<<8, 256, 0, stream>>>(bar);

    fused_lstm_kernel<<<NBLK, 256, 0, stream>>>(
        W_ih, W_hh, b_ih, b_hh, x, h0, c0,
        xpart, pre, xbuf1, xbuf2, bar, out);
}